// Round 7
// baseline (393.502 us; speedup 1.0000x reference)
//
#include <hip/hip_runtime.h>
#include <hip/hip_bf16.h>
#include <hip/hip_fp16.h>

#define RMAXF 2.0f
#define PI_F 3.14159265358979f

// clang ext_vector types — __builtin_nontemporal_load requires these
// (HIP_vector_type structs are rejected).
typedef float f32x4 __attribute__((ext_vector_type(4)));
typedef int   i32x4 __attribute__((ext_vector_type(4)));

// ---------------------------------------------------------------------------
// Kernel 1: per-atom packed params, ONE dword per atom:
//   parh[a] = half2{ A = |rep_prefactor[Z[a]]| , S = 1/|rep_scale[Z[a]]| }
// exponent identity: (R_i+R_j)/(R_i*R_j) = S_i + S_j.
// 200K atoms -> 800 KB, L2-resident. Divergent gathers are 4B/lane (the
// measured TA cost scales with per-lane dwords: r3 4B=160us, r4 8B=185us).
// ---------------------------------------------------------------------------
__global__ __launch_bounds__(256) void build_params(
    const int*   __restrict__ Z,
    const float* __restrict__ rep_scale,
    const float* __restrict__ rep_prefactor,
    __half2*     __restrict__ parh,
    int n_atoms)
{
    int a = blockIdx.x * blockDim.x + threadIdx.x;
    if (a < n_atoms) {
        int z = Z[a];
        float A = fabsf(rep_prefactor[z]);            // 476B tables: L1-resident
        float S = 1.0f / fabsf(rep_scale[z]);
        parh[a] = __floats2half2_rn(A, S);
    }
}

// ---------------------------------------------------------------------------
// Kernel 2: 8 edges per thread, no loop. 6x f32x4 (dr) + 4x i32x4 (idx)
// streaming loads marked nontemporal (zero reuse; keep L1 for par lines),
// then all 16 divergent 4B gathers hoisted so they are in flight together.
// ---------------------------------------------------------------------------
__global__ __launch_bounds__(256) void edge_kernel(
    const f32x4* __restrict__ dr4,
    const i32x4* __restrict__ idx_i4,
    const i32x4* __restrict__ idx_j4,
    const __half2* __restrict__ parh,
    float*        __restrict__ out,
    int n_oct, int n_edges)
{
    int q = blockIdx.x * blockDim.x + threadIdx.x;
    float acc = 0.0f;

    if (q < n_oct) {
        f32x4 va = __builtin_nontemporal_load(&dr4[6 * q + 0]);
        f32x4 vb = __builtin_nontemporal_load(&dr4[6 * q + 1]);
        f32x4 vc = __builtin_nontemporal_load(&dr4[6 * q + 2]);
        f32x4 vd = __builtin_nontemporal_load(&dr4[6 * q + 3]);
        f32x4 ve = __builtin_nontemporal_load(&dr4[6 * q + 4]);
        f32x4 vg = __builtin_nontemporal_load(&dr4[6 * q + 5]);
        i32x4 ia = __builtin_nontemporal_load(&idx_i4[2 * q + 0]);
        i32x4 ib = __builtin_nontemporal_load(&idx_i4[2 * q + 1]);
        i32x4 ja = __builtin_nontemporal_load(&idx_j4[2 * q + 0]);
        i32x4 jb = __builtin_nontemporal_load(&idx_j4[2 * q + 1]);

        int ii[8] = { ia.x, ia.y, ia.z, ia.w, ib.x, ib.y, ib.z, ib.w };
        int jj[8] = { ja.x, ja.y, ja.z, ja.w, jb.x, jb.y, jb.z, jb.w };

        // all 16 divergent 4B gathers issued back-to-back
        __half2 hi[8], hj[8];
        #pragma unroll
        for (int k = 0; k < 8; ++k) { hi[k] = parh[ii[k]]; hj[k] = parh[jj[k]]; }

        float d2[8];
        d2[0] = va.x * va.x + va.y * va.y + va.z * va.z;
        d2[1] = va.w * va.w + vb.x * vb.x + vb.y * vb.y;
        d2[2] = vb.z * vb.z + vb.w * vb.w + vc.x * vc.x;
        d2[3] = vc.y * vc.y + vc.z * vc.z + vc.w * vc.w;
        d2[4] = vd.x * vd.x + vd.y * vd.y + vd.z * vd.z;
        d2[5] = vd.w * vd.w + ve.x * ve.x + ve.y * ve.y;
        d2[6] = ve.z * ve.z + ve.w * ve.w + vg.x * vg.x;
        d2[7] = vg.y * vg.y + vg.z * vg.z + vg.w * vg.w;

        #pragma unroll
        for (int k = 0; k < 8; ++k) {
            float2 pi_ = __half22float2(hi[k]);
            float2 pj_ = __half22float2(hj[k]);
            // clip(sqrt(d2), 0.02, 2) == sqrt(clip(d2, 4e-4, 4))
            float d2c = fminf(fmaxf(d2[k], 4.0e-4f), 4.0f);
            float dr  = __builtin_amdgcn_sqrtf(d2c);
            // 0.5*(cos(pi*dr/2)+1) == cos^2(pi*dr/4)
            float cv  = __cosf((0.25f * PI_F) * dr);
            float e   = __expf(-dr * (pi_.y + pj_.y));
            float f   = pi_.x * pj_.x * e * __builtin_amdgcn_rcpf(d2c) * cv * cv;
            acc += (ii[k] != jj[k]) ? f : 0.0f;
        }
    }

    // tail (n_edges % 8) — empty for 12.8M edges, kept for generality
    if (blockIdx.x == gridDim.x - 1 && threadIdx.x == 0) {
        const float* drf = (const float*)dr4;
        const int* idx_i = (const int*)idx_i4;
        const int* idx_j = (const int*)idx_j4;
        for (int e = n_oct * 8; e < n_edges; ++e) {
            float x = drf[3 * e + 0], y = drf[3 * e + 1], z = drf[3 * e + 2];
            float d2c = fminf(fmaxf(x * x + y * y + z * z, 4.0e-4f), 4.0f);
            float dr  = sqrtf(d2c);
            float cv  = __cosf((0.25f * PI_F) * dr);
            int i = idx_i[e], j = idx_j[e];
            float2 pi_ = __half22float2(parh[i]);
            float2 pj_ = __half22float2(parh[j]);
            float f = pi_.x * pj_.x * __expf(-dr * (pi_.y + pj_.y)) / d2c * cv * cv;
            if (i != j) acc += f;
        }
    }

    // wave64 shuffle reduce -> block reduce -> one atomic per block
    #pragma unroll
    for (int off = 32; off > 0; off >>= 1)
        acc += __shfl_down(acc, off, 64);

    __shared__ float wsum[4];
    int lane = threadIdx.x & 63;
    int wid  = threadIdx.x >> 6;
    if (lane == 0) wsum[wid] = acc;
    __syncthreads();
    if (threadIdx.x == 0)
        atomicAdd(out, wsum[0] + wsum[1] + wsum[2] + wsum[3]);
}

// ---------------------------------------------------------------------------
// Fallback (ws too small or edge count not 8-aligned): LDS-table kernel,
// grid-stride scalar per edge. Correct but slower; not expected to be used.
// ---------------------------------------------------------------------------
__global__ __launch_bounds__(256) void edge_kernel_fallback(
    const float* __restrict__ drf,
    const int*   __restrict__ idx_i,
    const int*   __restrict__ idx_j,
    const int*   __restrict__ Z,
    const float* __restrict__ rep_scale,
    const float* __restrict__ rep_prefactor,
    float*       __restrict__ out,
    int n_edges)
{
    __shared__ float2 tab[128];
    for (int t = threadIdx.x; t < 119; t += blockDim.x)
        tab[t] = make_float2(fabsf(rep_prefactor[t]),
                             1.0f / fabsf(rep_scale[t]));
    __syncthreads();

    float acc = 0.0f;
    const int stride = gridDim.x * blockDim.x;
    for (int e = blockIdx.x * blockDim.x + threadIdx.x; e < n_edges; e += stride) {
        float x = drf[3 * e + 0], y = drf[3 * e + 1], z = drf[3 * e + 2];
        float d2c = fminf(fmaxf(x * x + y * y + z * z, 4.0e-4f), 4.0f);
        float dr  = __builtin_amdgcn_sqrtf(d2c);
        float cv  = __cosf((0.25f * PI_F) * dr);
        int i = idx_i[e], j = idx_j[e];
        float2 pi_ = tab[Z[i]], pj_ = tab[Z[j]];
        float f = pi_.x * pj_.x * __expf(-dr * (pi_.y + pj_.y))
                  * __builtin_amdgcn_rcpf(d2c) * cv * cv;
        acc += (i != j) ? f : 0.0f;
    }

    #pragma unroll
    for (int off = 32; off > 0; off >>= 1)
        acc += __shfl_down(acc, off, 64);
    __shared__ float wsum[4];
    int lane = threadIdx.x & 63;
    int wid  = threadIdx.x >> 6;
    if (lane == 0) wsum[wid] = acc;
    __syncthreads();
    if (threadIdx.x == 0)
        atomicAdd(out, wsum[0] + wsum[1] + wsum[2] + wsum[3]);
}

extern "C" void kernel_launch(void* const* d_in, const int* in_sizes, int n_in,
                              void* d_out, int out_size, void* d_ws, size_t ws_size,
                              hipStream_t stream) {
    // inputs: 0=R, 1=dr_vec, 2=Z, 3=idx, 4=box, 5=properties, 6=rep_scale, 7=rep_prefactor
    const float* dr_vec        = (const float*)d_in[1];
    const int*   Z             = (const int*)d_in[2];
    const int*   idx           = (const int*)d_in[3];
    const float* rep_scale     = (const float*)d_in[6];
    const float* rep_prefactor = (const float*)d_in[7];
    float* out = (float*)d_out;

    const int n_atoms = in_sizes[2];
    const int n_edges = in_sizes[3] / 2;       // idx is (2, N_EDGES)
    const int n_oct   = n_edges / 8;
    const int* idx_i = idx;
    const int* idx_j = idx + n_edges;

    // d_out poisoned 0xAA before every replay — zero on-stream
    (void)hipMemsetAsync(d_out, 0, sizeof(float), stream);

    const size_t par_bytes = (size_t)n_atoms * sizeof(__half2);
    const bool aligned = ((n_edges & 7) == 0);   // i32x4 casts + 8-edge groups

    if (ws_size >= par_bytes && aligned) {
        __half2* parh = (__half2*)d_ws;          // d_ws poisoned too — rebuilt every call
        build_params<<<(n_atoms + 255) / 256, 256, 0, stream>>>(
            Z, rep_scale, rep_prefactor, parh, n_atoms);
        edge_kernel<<<(n_oct + 255) / 256, 256, 0, stream>>>(
            (const f32x4*)dr_vec, (const i32x4*)idx_i, (const i32x4*)idx_j,
            parh, out, n_oct, n_edges);
    } else {
        int blocks = (n_edges + 255) / 256;
        if (blocks > 4096) blocks = 4096;
        edge_kernel_fallback<<<blocks, 256, 0, stream>>>(
            dr_vec, idx_i, idx_j, Z, rep_scale, rep_prefactor, out, n_edges);
    }
}

// Round 8
// 334.635 us; speedup vs baseline: 1.1759x; 1.1759x over previous
//
#include <hip/hip_runtime.h>
#include <hip/hip_bf16.h>
#include <hip/hip_fp16.h>

#define RMAXF 2.0f
#define PI_F 3.14159265358979f

// clang ext_vector types — __builtin_nontemporal_load requires these
typedef float f32x4 __attribute__((ext_vector_type(4)));
typedef int   i32x4 __attribute__((ext_vector_type(4)));

// LDS-resident Z coverage (bytes). 162304 + 120*8 + 16*4 = 163328 <= 163840.
#define LDS_COVER 162304

// ---------------------------------------------------------------------------
// Prologue: Z (int32, values < 119) -> uint8. 200 KB table; the edge kernel
// stages most of it to LDS, and tail atoms (>= cover) gather from this
// compact 37 KB working set (near-L1-resident).
// ---------------------------------------------------------------------------
__global__ __launch_bounds__(256) void z_to_u8(
    const int* __restrict__ Z, unsigned char* __restrict__ zu8, int n)
{
    int i = blockIdx.x * blockDim.x + threadIdx.x;
    if (i < n) zu8[i] = (unsigned char)Z[i];
}

// ---------------------------------------------------------------------------
// Main kernel. Rationale (r3/r4/r7 evidence): divergent GLOBAL gathers cost
// ~256 cyc per wave64 instruction regardless of size/hit-tier -> 2/edge was
// the entire 160-185us. LDS random lookups are ~free (r3). So: Z as uint8 in
// LDS (81% of atoms), param tab (float2[119]) in LDS, tail 19% gathers from
// a 37KB global uint8 table. 1024 thr/block, 160KB LDS -> 16 waves/CU.
// ---------------------------------------------------------------------------
__global__ __launch_bounds__(1024) void edge_kernel_lds(
    const f32x4* __restrict__ dr4,
    const i32x4* __restrict__ idx_i4,
    const i32x4* __restrict__ idx_j4,
    const unsigned char* __restrict__ zu8,
    const float* __restrict__ rep_scale,
    const float* __restrict__ rep_prefactor,
    float*       __restrict__ out,
    int n_oct, int n_edges, int cover)
{
    __shared__ unsigned char zs[LDS_COVER];
    __shared__ float2 tab[120];
    __shared__ float wsum[16];

    // stage per-element param tab (476B tables: L1-resident broadcasts)
    for (int t = threadIdx.x; t < 119; t += blockDim.x)
        tab[t] = make_float2(fabsf(rep_prefactor[t]),
                             1.0f / fabsf(rep_scale[t]));
    // stage zs cooperatively, 16B per thread-iteration (cover % 16 == 0)
    {
        const i32x4* zsrc = (const i32x4*)zu8;
        i32x4* zdst = (i32x4*)zs;
        const int nvec = cover >> 4;
        for (int t = threadIdx.x; t < nvec; t += blockDim.x)
            zdst[t] = zsrc[t];
    }
    __syncthreads();

    float acc = 0.0f;
    const int stride = gridDim.x * blockDim.x;

    for (int q = blockIdx.x * blockDim.x + threadIdx.x; q < n_oct; q += stride) {
        // 8 edges: 6x f32x4 dr_vec + 4x i32x4 idx, nontemporal (zero reuse;
        // keep L1/L2 lines for the zu8 tail table)
        f32x4 va = __builtin_nontemporal_load(&dr4[6 * q + 0]);
        f32x4 vb = __builtin_nontemporal_load(&dr4[6 * q + 1]);
        f32x4 vc = __builtin_nontemporal_load(&dr4[6 * q + 2]);
        f32x4 vd = __builtin_nontemporal_load(&dr4[6 * q + 3]);
        f32x4 ve = __builtin_nontemporal_load(&dr4[6 * q + 4]);
        f32x4 vg = __builtin_nontemporal_load(&dr4[6 * q + 5]);
        i32x4 ia = __builtin_nontemporal_load(&idx_i4[2 * q + 0]);
        i32x4 ib = __builtin_nontemporal_load(&idx_i4[2 * q + 1]);
        i32x4 ja = __builtin_nontemporal_load(&idx_j4[2 * q + 0]);
        i32x4 jb = __builtin_nontemporal_load(&idx_j4[2 * q + 1]);

        int ii[8] = { ia.x, ia.y, ia.z, ia.w, ib.x, ib.y, ib.z, ib.w };
        int jj[8] = { ja.x, ja.y, ja.z, ja.w, jb.x, jb.y, jb.z, jb.w };

        // Z lookups: LDS for a < cover (81%), global u8 tail otherwise
        int zi[8], zj[8];
        #pragma unroll
        for (int k = 0; k < 8; ++k) {
            int a = ii[k], b = jj[k];
            zi[k] = (a < cover) ? (int)zs[a] : (int)zu8[a];
            zj[k] = (b < cover) ? (int)zs[b] : (int)zu8[b];
        }

        float d2[8];
        d2[0] = va.x * va.x + va.y * va.y + va.z * va.z;
        d2[1] = va.w * va.w + vb.x * vb.x + vb.y * vb.y;
        d2[2] = vb.z * vb.z + vb.w * vb.w + vc.x * vc.x;
        d2[3] = vc.y * vc.y + vc.z * vc.z + vc.w * vc.w;
        d2[4] = vd.x * vd.x + vd.y * vd.y + vd.z * vd.z;
        d2[5] = vd.w * vd.w + ve.x * ve.x + ve.y * ve.y;
        d2[6] = ve.z * ve.z + ve.w * ve.w + vg.x * vg.x;
        d2[7] = vg.y * vg.y + vg.z * vg.z + vg.w * vg.w;

        #pragma unroll
        for (int k = 0; k < 8; ++k) {
            float2 pi_ = tab[zi[k]];
            float2 pj_ = tab[zj[k]];
            // clip(sqrt(d2), 0.02, 2) == sqrt(clip(d2, 4e-4, 4))
            float d2c = fminf(fmaxf(d2[k], 4.0e-4f), 4.0f);
            float dr  = __builtin_amdgcn_sqrtf(d2c);
            // 0.5*(cos(pi*dr/2)+1) == cos^2(pi*dr/4)
            float cv  = __cosf((0.25f * PI_F) * dr);
            float e   = __expf(-dr * (pi_.y + pj_.y));
            float f   = pi_.x * pj_.x * e * __builtin_amdgcn_rcpf(d2c) * cv * cv;
            acc += (ii[k] != jj[k]) ? f : 0.0f;
        }
    }

    // tail (n_edges % 8) — empty for 12.8M edges
    if (blockIdx.x == 0 && threadIdx.x == 0) {
        const float* drf = (const float*)dr4;
        const int* idx_i = (const int*)idx_i4;
        const int* idx_j = (const int*)idx_j4;
        for (int e = n_oct * 8; e < n_edges; ++e) {
            float x = drf[3 * e + 0], y = drf[3 * e + 1], z = drf[3 * e + 2];
            float d2c = fminf(fmaxf(x * x + y * y + z * z, 4.0e-4f), 4.0f);
            float dr  = sqrtf(d2c);
            float cv  = __cosf((0.25f * PI_F) * dr);
            int i = idx_i[e], j = idx_j[e];
            float2 pi_ = tab[zu8[i]];
            float2 pj_ = tab[zu8[j]];
            float f = pi_.x * pj_.x * __expf(-dr * (pi_.y + pj_.y)) / d2c * cv * cv;
            if (i != j) acc += f;
        }
    }

    // wave64 shuffle reduce -> 16-wave block reduce -> one atomic per block
    #pragma unroll
    for (int off = 32; off > 0; off >>= 1)
        acc += __shfl_down(acc, off, 64);

    int lane = threadIdx.x & 63;
    int wid  = threadIdx.x >> 6;
    if (lane == 0) wsum[wid] = acc;
    __syncthreads();
    if (threadIdx.x == 0) {
        float s = 0.0f;
        #pragma unroll
        for (int w = 0; w < 16; ++w) s += wsum[w];
        atomicAdd(out, s);
    }
}

// ---------------------------------------------------------------------------
// Fallback (ws too small or edge count not 8-aligned): Z int32 gather +
// LDS tab, grid-stride scalar. Correct but slower; not expected to be used.
// ---------------------------------------------------------------------------
__global__ __launch_bounds__(256) void edge_kernel_fallback(
    const float* __restrict__ drf,
    const int*   __restrict__ idx_i,
    const int*   __restrict__ idx_j,
    const int*   __restrict__ Z,
    const float* __restrict__ rep_scale,
    const float* __restrict__ rep_prefactor,
    float*       __restrict__ out,
    int n_edges)
{
    __shared__ float2 tab[128];
    for (int t = threadIdx.x; t < 119; t += blockDim.x)
        tab[t] = make_float2(fabsf(rep_prefactor[t]),
                             1.0f / fabsf(rep_scale[t]));
    __syncthreads();

    float acc = 0.0f;
    const int stride = gridDim.x * blockDim.x;
    for (int e = blockIdx.x * blockDim.x + threadIdx.x; e < n_edges; e += stride) {
        float x = drf[3 * e + 0], y = drf[3 * e + 1], z = drf[3 * e + 2];
        float d2c = fminf(fmaxf(x * x + y * y + z * z, 4.0e-4f), 4.0f);
        float dr  = __builtin_amdgcn_sqrtf(d2c);
        float cv  = __cosf((0.25f * PI_F) * dr);
        int i = idx_i[e], j = idx_j[e];
        float2 pi_ = tab[Z[i]], pj_ = tab[Z[j]];
        float f = pi_.x * pj_.x * __expf(-dr * (pi_.y + pj_.y))
                  * __builtin_amdgcn_rcpf(d2c) * cv * cv;
        acc += (i != j) ? f : 0.0f;
    }

    #pragma unroll
    for (int off = 32; off > 0; off >>= 1)
        acc += __shfl_down(acc, off, 64);
    __shared__ float wsum[4];
    int lane = threadIdx.x & 63;
    int wid  = threadIdx.x >> 6;
    if (lane == 0) wsum[wid] = acc;
    __syncthreads();
    if (threadIdx.x == 0)
        atomicAdd(out, wsum[0] + wsum[1] + wsum[2] + wsum[3]);
}

extern "C" void kernel_launch(void* const* d_in, const int* in_sizes, int n_in,
                              void* d_out, int out_size, void* d_ws, size_t ws_size,
                              hipStream_t stream) {
    // inputs: 0=R, 1=dr_vec, 2=Z, 3=idx, 4=box, 5=properties, 6=rep_scale, 7=rep_prefactor
    const float* dr_vec        = (const float*)d_in[1];
    const int*   Z             = (const int*)d_in[2];
    const int*   idx           = (const int*)d_in[3];
    const float* rep_scale     = (const float*)d_in[6];
    const float* rep_prefactor = (const float*)d_in[7];
    float* out = (float*)d_out;

    const int n_atoms = in_sizes[2];
    const int n_edges = in_sizes[3] / 2;       // idx is (2, N_EDGES)
    const int n_oct   = n_edges / 8;
    const int* idx_i = idx;
    const int* idx_j = idx + n_edges;

    // d_out poisoned 0xAA before every replay — zero on-stream
    (void)hipMemsetAsync(d_out, 0, sizeof(float), stream);

    const bool aligned = ((n_edges & 7) == 0);

    if (ws_size >= (size_t)n_atoms && aligned) {
        unsigned char* zu8 = (unsigned char*)d_ws;   // rebuilt every call
        z_to_u8<<<(n_atoms + 255) / 256, 256, 0, stream>>>(Z, zu8, n_atoms);

        int cover = n_atoms < LDS_COVER ? (n_atoms & ~15) : LDS_COVER;
        int blocks = (n_oct + 1023) / 1024;
        if (blocks > 256) blocks = 256;              // 1 block/CU (160KB LDS)
        edge_kernel_lds<<<blocks, 1024, 0, stream>>>(
            (const f32x4*)dr_vec, (const i32x4*)idx_i, (const i32x4*)idx_j,
            zu8, rep_scale, rep_prefactor, out, n_oct, n_edges, cover);
    } else {
        int blocks = (n_edges + 255) / 256;
        if (blocks > 4096) blocks = 4096;
        edge_kernel_fallback<<<blocks, 256, 0, stream>>>(
            dr_vec, idx_i, idx_j, Z, rep_scale, rep_prefactor, out, n_edges);
    }
}